// Round 3
// baseline (994.088 us; speedup 1.0000x reference)
//
#include <hip/hip_runtime.h>
#include <hip/hip_bf16.h>

#define NB 2
#define SEQ 2048
#define DMODEL 2048
#define NH 16
#define HD 128
#define SM_SCALE 0.08838834764831845f

using bf16x8 = __attribute__((ext_vector_type(8))) __bf16;
using f32x4  = __attribute__((ext_vector_type(4))) float;

#define MFMA16 __builtin_amdgcn_mfma_f32_16x16x32_bf16

__device__ inline unsigned short f2b(float f) {
    unsigned u = __builtin_bit_cast(unsigned, f);
    u += 0x7FFF + ((u >> 16) & 1);
    return (unsigned short)(u >> 16);
}
__device__ inline float b2f(unsigned short h) {
    return __builtin_bit_cast(float, (unsigned)h << 16);
}

// ---------------- cast fp32 -> bf16, 4 elems/thread ----------------
__global__ void cast_f2b(const float* __restrict__ src, unsigned short* __restrict__ dst, int n) {
    int i = (blockIdx.x * 256 + threadIdx.x) * 4;
    if (i + 3 < n) {
        float4 v = *reinterpret_cast<const float4*>(src + i);
        ushort4 o;
        o.x = f2b(v.x); o.y = f2b(v.y); o.z = f2b(v.z); o.w = f2b(v.w);
        *reinterpret_cast<ushort4*>(dst + i) = o;
    }
}

// ---------------- GEMM: C[M,N] = A[M,K] * Bw[N,K]^T, bf16 in, fp32 acc ----------------
// block 256 = 4 waves, block tile 128x128, wave tile 64x64 (4x4 16x16 frags)
template<int OUT_BF16>
__global__ __launch_bounds__(256) void gemm_bt(const unsigned short* __restrict__ A,
                                               const unsigned short* __restrict__ Bw,
                                               void* __restrict__ Cout,
                                               int M, int N, int K) {
    int tid = threadIdx.x;
    int lane = tid & 63;
    int w = tid >> 6;
    int row0 = blockIdx.y * 128 + (w >> 1) * 64;
    int col0 = blockIdx.x * 128 + (w & 1) * 64;
    int lr = lane & 15;
    int lk = (lane >> 4) * 8;

    f32x4 acc[4][4] = {};
    const unsigned short* Ap = A + (size_t)(row0 + lr) * K + lk;
    const unsigned short* Bp = Bw + (size_t)(col0 + lr) * K + lk;

    for (int k = 0; k < K; k += 32) {
        bf16x8 a[4], b[4];
#pragma unroll
        for (int i = 0; i < 4; i++) a[i] = *reinterpret_cast<const bf16x8*>(Ap + (size_t)i * 16 * K + k);
#pragma unroll
        for (int j = 0; j < 4; j++) b[j] = *reinterpret_cast<const bf16x8*>(Bp + (size_t)j * 16 * K + k);
#pragma unroll
        for (int i = 0; i < 4; i++)
#pragma unroll
            for (int j = 0; j < 4; j++)
                acc[i][j] = MFMA16(a[i], b[j], acc[i][j], 0, 0, 0);
    }

    int orow = (lane >> 4) * 4;
#pragma unroll
    for (int i = 0; i < 4; i++) {
#pragma unroll
        for (int j = 0; j < 4; j++) {
            int r0 = row0 + i * 16 + orow;
            int c  = col0 + j * 16 + lr;
#pragma unroll
            for (int r = 0; r < 4; r++) {
                float v = acc[i][j][r];
                if (OUT_BF16)
                    ((unsigned short*)Cout)[(size_t)(r0 + r) * N + c] = f2b(v);
                else
                    ((float*)Cout)[(size_t)(r0 + r) * N + c] = v;
            }
        }
    }
}

// ---------------- RoPE + rearrange Q,K: qkv[4096][6144] -> qb/kb [B][H][S][HD] ----------------
__global__ void rope_qk(const unsigned short* __restrict__ qkv,
                        unsigned short* __restrict__ qb,
                        unsigned short* __restrict__ kb) {
    int idx = blockIdx.x * 256 + threadIdx.x;   // B*S*H*64 = 4194304
    int i = idx & 63;            // pair index
    int h = (idx >> 6) & 15;
    int t = idx >> 10;           // 0..4095
    int s = t & (SEQ - 1);
    int b = t >> 11;

    float inv = exp2f(-13.287712379549449f * (float)i * (1.0f / 64.0f));
    float ang = (float)s * inv;
    float sn, cs;
    sincosf(ang, &sn, &cs);

    const unsigned short* base = qkv + (size_t)t * 6144 + h * 128 + 2 * i;
    unsigned qv = *reinterpret_cast<const unsigned*>(base);
    unsigned kv = *reinterpret_cast<const unsigned*>(base + 2048);

    float qe = b2f((unsigned short)(qv & 0xFFFF));
    float qo = b2f((unsigned short)(qv >> 16));
    float ke = b2f((unsigned short)(kv & 0xFFFF));
    float ko = b2f((unsigned short)(kv >> 16));

    float qe2 = (qe * cs - qo * sn) * SM_SCALE;
    float qo2 = (qe * sn + qo * cs) * SM_SCALE;
    float ke2 = ke * cs - ko * sn;
    float ko2 = ke * sn + ko * cs;

    size_t o = ((size_t)(b * NH + h) * SEQ + s) * HD + 2 * i;
    *reinterpret_cast<unsigned*>(qb + o) = (unsigned)f2b(qe2) | ((unsigned)f2b(qo2) << 16);
    *reinterpret_cast<unsigned*>(kb + o) = (unsigned)f2b(ke2) | ((unsigned)f2b(ko2) << 16);
}

// ---------------- V rearrange: qkv -> vt [B][H][HD][S] ----------------
__global__ void v_rearr(const unsigned short* __restrict__ qkv, unsigned short* __restrict__ vt) {
    int idx = blockIdx.x * 256 + threadIdx.x;   // B*H*HD*(S/4) = 2097152
    int s4 = (idx & 511) * 4;
    int d  = (idx >> 9) & 127;
    int h  = (idx >> 16) & 15;
    int b  = idx >> 20;
    ushort4 o;
    size_t rbase = (size_t)(b * SEQ + s4) * 6144 + 4096 + h * 128 + d;
    o.x = qkv[rbase];
    o.y = qkv[rbase + 6144];
    o.z = qkv[rbase + 2 * 6144];
    o.w = qkv[rbase + 3 * 6144];
    *reinterpret_cast<ushort4*>(vt + ((size_t)(b * NH + h) * HD + d) * SEQ + s4) = o;
}

// ---------------- flash attention, causal; 1 wave = 16 q rows ----------------
__global__ __launch_bounds__(256) void attn(const unsigned short* __restrict__ Q,
                                            const unsigned short* __restrict__ Kb,
                                            const unsigned short* __restrict__ Vt,
                                            unsigned short* __restrict__ O) {
    __shared__ unsigned short plds[4][16][32];
    int tid = threadIdx.x;
    int lane = tid & 63;
    int w = tid >> 6;
    int gw = blockIdx.x * 4 + w;       // 0..4095
    int qt = gw & 127;
    int h  = (gw >> 7) & 15;
    int b  = gw >> 11;
    int q0 = qt * 16;
    int lr = lane & 15;
    int lk = (lane >> 4) * 8;
    int orow = (lane >> 4) * 4;

    const unsigned short* Qp = Q  + (size_t)(b * NH + h) * SEQ * HD;
    const unsigned short* Kp = Kb + (size_t)(b * NH + h) * SEQ * HD;
    const unsigned short* Vp = Vt + (size_t)(b * NH + h) * HD * SEQ;

    bf16x8 qf[4];
#pragma unroll
    for (int kb = 0; kb < 4; kb++)
        qf[kb] = *reinterpret_cast<const bf16x8*>(Qp + (size_t)(q0 + lr) * HD + kb * 32 + lk);

    f32x4 oacc[8] = {};
    float m[4], l[4];
#pragma unroll
    for (int r = 0; r < 4; r++) { m[r] = -1e30f; l[r] = 0.0f; }

    int ntile = (q0 + 15) / 32 + 1;
    for (int t = 0; t < ntile; ++t) {
        int kv0 = t * 32;
        f32x4 s0 = {}, s1 = {};
#pragma unroll
        for (int kb = 0; kb < 4; kb++) {
            bf16x8 k0 = *reinterpret_cast<const bf16x8*>(Kp + (size_t)(kv0 + lr) * HD + kb * 32 + lk);
            bf16x8 k1 = *reinterpret_cast<const bf16x8*>(Kp + (size_t)(kv0 + 16 + lr) * HD + kb * 32 + lk);
            s0 = MFMA16(qf[kb], k0, s0, 0, 0, 0);
            s1 = MFMA16(qf[kb], k1, s1, 0, 0, 0);
        }

        int c0 = kv0 + lr, c1 = c0 + 16;
#pragma unroll
        for (int r = 0; r < 4; r++) {
            int qi = q0 + orow + r;
            float v0 = (c0 <= qi) ? s0[r] : -1e30f;
            float v1 = (c1 <= qi) ? s1[r] : -1e30f;
            float mx = fmaxf(v0, v1);
#pragma unroll
            for (int d = 1; d < 16; d <<= 1) mx = fmaxf(mx, __shfl_xor(mx, d));
            float mn = fmaxf(m[r], mx);
            float sc = expf(m[r] - mn);
            m[r] = mn;
            float p0 = expf(v0 - mn);
            float p1 = expf(v1 - mn);
            float rs = p0 + p1;
#pragma unroll
            for (int d = 1; d < 16; d <<= 1) rs += __shfl_xor(rs, d);
            l[r] = l[r] * sc + rs;
#pragma unroll
            for (int db = 0; db < 8; db++) oacc[db][r] *= sc;
            // stash P into LDS (bf16), row = q (0..15), col = kv (0..31)
            unsigned short* pl = &plds[w][0][0];
            pl[(orow + r) * 32 + lr]      = f2b(p0);
            pl[(orow + r) * 32 + lr + 16] = f2b(p1);
        }

        asm volatile("s_waitcnt lgkmcnt(0)" ::: "memory");
        __builtin_amdgcn_sched_barrier(0);
        bf16x8 pf = *reinterpret_cast<const bf16x8*>(&plds[w][0][0] + lr * 32 + lk);

#pragma unroll
        for (int db = 0; db < 8; db++) {
            bf16x8 vf = *reinterpret_cast<const bf16x8*>(Vp + (size_t)(db * 16 + lr) * SEQ + kv0 + lk);
            oacc[db] = MFMA16(pf, vf, oacc[db], 0, 0, 0);
        }
    }

#pragma unroll
    for (int r = 0; r < 4; r++) {
        float inv = 1.0f / l[r];
        int srow = q0 + orow + r;
        unsigned short* op = O + (size_t)(b * SEQ + srow) * DMODEL + h * HD;
#pragma unroll
        for (int db = 0; db < 8; db++)
            op[db * 16 + lr] = f2b(oacc[db][r] * inv);
    }
}

extern "C" void kernel_launch(void* const* d_in, const int* in_sizes, int n_in,
                              void* d_out, int out_size, void* d_ws, size_t ws_size,
                              hipStream_t stream) {
    const float* x   = (const float*)d_in[0];
    const float* wqk = (const float*)d_in[1];
    const float* wv  = (const float*)d_in[2];
    const float* wo  = (const float*)d_in[3];

    unsigned short* xb  = (unsigned short*)d_ws;            // [4096][2048]
    unsigned short* wb  = xb  + (size_t)8388608;            // [8192][2048]: wqk | wv | wo
    unsigned short* qkv = wb  + (size_t)16777216;           // [4096][6144]
    unsigned short* qb  = qkv + (size_t)25165824;           // [B][H][S][HD]
    unsigned short* kb  = qb  + (size_t)8388608;
    unsigned short* vt  = kb  + (size_t)8388608;            // [B][H][HD][S]
    unsigned short* ao  = vt  + (size_t)8388608;            // [4096][2048]

    cast_f2b<<<8192, 256, 0, stream>>>(x,   xb, 8388608);
    cast_f2b<<<8192, 256, 0, stream>>>(wqk, wb, 8388608);
    cast_f2b<<<4096, 256, 0, stream>>>(wv,  wb + 8388608, 4194304);
    cast_f2b<<<4096, 256, 0, stream>>>(wo,  wb + 12582912, 4194304);

    // QKV projection: [4096,2048] x [6144,2048]^T -> [4096,6144] bf16
    gemm_bt<1><<<dim3(48, 32), 256, 0, stream>>>(xb, wb, (void*)qkv, 4096, 6144, 2048);

    rope_qk<<<16384, 256, 0, stream>>>(qkv, qb, kb);
    v_rearr<<<8192, 256, 0, stream>>>(qkv, vt);

    attn<<<1024, 256, 0, stream>>>(qb, kb, vt, ao);

    // out projection: [4096,2048] x [2048,2048]^T -> [4096,2048] fp32
    gemm_bt<0><<<dim3(16, 32), 256, 0, stream>>>(ao, wb + 12582912, d_out, 4096, 2048, 2048);
}

// Round 4
// 774.421 us; speedup vs baseline: 1.2837x; 1.2837x over previous
//
#include <hip/hip_runtime.h>
#include <hip/hip_bf16.h>

#define NB 2
#define SEQ 2048
#define DMODEL 2048
#define NH 16
#define HD 128
#define SM_SCALE 0.08838834764831845f

using bf16x8 = __attribute__((ext_vector_type(8))) __bf16;
using f32x4  = __attribute__((ext_vector_type(4))) float;

#define MFMA16 __builtin_amdgcn_mfma_f32_16x16x32_bf16

__device__ inline unsigned short f2b(float f) {
    unsigned u = __builtin_bit_cast(unsigned, f);
    u += 0x7FFF + ((u >> 16) & 1);
    return (unsigned short)(u >> 16);
}
__device__ inline float b2f(unsigned short h) {
    return __builtin_bit_cast(float, (unsigned)h << 16);
}

// ---------------- cast fp32 -> bf16, 4 elems/thread ----------------
__global__ void cast_f2b(const float* __restrict__ src, unsigned short* __restrict__ dst, int n) {
    int i = (blockIdx.x * 256 + threadIdx.x) * 4;
    if (i + 3 < n) {
        float4 v = *reinterpret_cast<const float4*>(src + i);
        ushort4 o;
        o.x = f2b(v.x); o.y = f2b(v.y); o.z = f2b(v.z); o.w = f2b(v.w);
        *reinterpret_cast<ushort4*>(dst + i) = o;
    }
}

// ---------------- GEMM: C[M,N] = A[M,K] * Bw[N,K]^T, bf16 in, fp32 acc ----------------
template<int OUT_BF16>
__global__ __launch_bounds__(256) void gemm_bt(const unsigned short* __restrict__ A,
                                               const unsigned short* __restrict__ Bw,
                                               void* __restrict__ Cout,
                                               int M, int N, int K) {
    int tid = threadIdx.x;
    int lane = tid & 63;
    int w = tid >> 6;
    int row0 = blockIdx.y * 128 + (w >> 1) * 64;
    int col0 = blockIdx.x * 128 + (w & 1) * 64;
    int lr = lane & 15;
    int lk = (lane >> 4) * 8;

    f32x4 acc[4][4] = {};
    const unsigned short* Ap = A + (size_t)(row0 + lr) * K + lk;
    const unsigned short* Bp = Bw + (size_t)(col0 + lr) * K + lk;

    for (int k = 0; k < K; k += 32) {
        bf16x8 a[4], b[4];
#pragma unroll
        for (int i = 0; i < 4; i++) a[i] = *reinterpret_cast<const bf16x8*>(Ap + (size_t)i * 16 * K + k);
#pragma unroll
        for (int j = 0; j < 4; j++) b[j] = *reinterpret_cast<const bf16x8*>(Bp + (size_t)j * 16 * K + k);
#pragma unroll
        for (int i = 0; i < 4; i++)
#pragma unroll
            for (int j = 0; j < 4; j++)
                acc[i][j] = MFMA16(a[i], b[j], acc[i][j], 0, 0, 0);
    }

    int orow = (lane >> 4) * 4;
#pragma unroll
    for (int i = 0; i < 4; i++) {
#pragma unroll
        for (int j = 0; j < 4; j++) {
            int r0 = row0 + i * 16 + orow;
            int c  = col0 + j * 16 + lr;
#pragma unroll
            for (int r = 0; r < 4; r++) {
                float v = acc[i][j][r];
                if (OUT_BF16)
                    ((unsigned short*)Cout)[(size_t)(r0 + r) * N + c] = f2b(v);
                else
                    ((float*)Cout)[(size_t)(r0 + r) * N + c] = v;
            }
        }
    }
}

// ---------------- RoPE + rearrange Q,K ----------------
__global__ void rope_qk(const unsigned short* __restrict__ qkv,
                        unsigned short* __restrict__ qb,
                        unsigned short* __restrict__ kb) {
    int idx = blockIdx.x * 256 + threadIdx.x;
    int i = idx & 63;
    int h = (idx >> 6) & 15;
    int t = idx >> 10;
    int s = t & (SEQ - 1);
    int b = t >> 11;

    float inv = exp2f(-13.287712379549449f * (float)i * (1.0f / 64.0f));
    float ang = (float)s * inv;
    float sn, cs;
    sincosf(ang, &sn, &cs);

    const unsigned short* base = qkv + (size_t)t * 6144 + h * 128 + 2 * i;
    unsigned qv = *reinterpret_cast<const unsigned*>(base);
    unsigned kv = *reinterpret_cast<const unsigned*>(base + 2048);

    float qe = b2f((unsigned short)(qv & 0xFFFF));
    float qo = b2f((unsigned short)(qv >> 16));
    float ke = b2f((unsigned short)(kv & 0xFFFF));
    float ko = b2f((unsigned short)(kv >> 16));

    float qe2 = (qe * cs - qo * sn) * SM_SCALE;
    float qo2 = (qe * sn + qo * cs) * SM_SCALE;
    float ke2 = ke * cs - ko * sn;
    float ko2 = ke * sn + ko * cs;

    size_t o = ((size_t)(b * NH + h) * SEQ + s) * HD + 2 * i;
    *reinterpret_cast<unsigned*>(qb + o) = (unsigned)f2b(qe2) | ((unsigned)f2b(qo2) << 16);
    *reinterpret_cast<unsigned*>(kb + o) = (unsigned)f2b(ke2) | ((unsigned)f2b(ko2) << 16);
}

// ---------------- V rearrange: qkv -> vt [B][H][HD][S] ----------------
__global__ void v_rearr(const unsigned short* __restrict__ qkv, unsigned short* __restrict__ vt) {
    int idx = blockIdx.x * 256 + threadIdx.x;
    int s4 = (idx & 511) * 4;
    int d  = (idx >> 9) & 127;
    int h  = (idx >> 16) & 15;
    int b  = idx >> 20;
    ushort4 o;
    size_t rbase = (size_t)(b * SEQ + s4) * 6144 + 4096 + h * 128 + d;
    o.x = qkv[rbase];
    o.y = qkv[rbase + 6144];
    o.z = qkv[rbase + 2 * 6144];
    o.w = qkv[rbase + 3 * 6144];
    *reinterpret_cast<ushort4*>(vt + ((size_t)(b * NH + h) * HD + d) * SEQ + s4) = o;
}

// ---------------- flash attention v2: 4 waves/block, 32 q-rows/wave, KVBLK=64 ----------------
// K tile [64][128] staged in LDS (XOR-swizzled, double-buffered, shared by 4 waves).
// P tile per wave [32][64] in LDS (XOR-swizzled). V read from global (Vt layout, L2-resident).
__global__ __launch_bounds__(256) void attn2(const unsigned short* __restrict__ Q,
                                             const unsigned short* __restrict__ Kb,
                                             const unsigned short* __restrict__ Vt,
                                             unsigned short* __restrict__ O) {
    __shared__ __align__(16) char lds[49152];   // 2x16KB K dbuf + 4x4KB P

    int tid = threadIdx.x;
    int lane = tid & 63;
    int w = tid >> 6;
    int bid = blockIdx.x;
    // complementary pairing: bid i and i+256 have qblk summing to 15 (uniform work/CU)
    int qblk = (bid < 256) ? (15 - (bid >> 5)) : ((bid - 256) >> 5);
    int bh = bid & 31;
    int wq0 = qblk * 128 + w * 32;
    int lr = lane & 15;
    int g  = lane >> 4;
    int lk = g * 8;
    int orow = g * 4;

    const unsigned short* Qp = Q  + (size_t)bh * SEQ * HD;
    const unsigned short* Kp = Kb + (size_t)bh * SEQ * HD;
    const unsigned short* Vp = Vt + (size_t)bh * HD * SEQ;
    char* pl = lds + 32768 + w * 4096;

    // Q fragments (32 rows x 128)
    bf16x8 qf[2][4];
#pragma unroll
    for (int f = 0; f < 2; f++)
#pragma unroll
        for (int kb = 0; kb < 4; kb++)
            qf[f][kb] = *reinterpret_cast<const bf16x8*>(Qp + (size_t)(wq0 + f * 16 + lr) * HD + kb * 32 + lk);

    f32x4 oacc[2][8] = {};
    float m[2][4], l[2][4];
#pragma unroll
    for (int f = 0; f < 2; f++)
#pragma unroll
        for (int r = 0; r < 4; r++) { m[f][r] = -1e30f; l[f][r] = 0.0f; }

    int TRIPS = 2 * qblk + 2;

    // staging geometry: 1024 16B-chunks; thread handles chunks tid + c*256
    int srow[4], scin[4];
#pragma unroll
    for (int c = 0; c < 4; c++) {
        int chunk = tid + c * 256;
        srow[c] = chunk >> 4;
        scin[c] = chunk & 15;
    }

    // prologue: stage tile 0 into buf 0
    {
        bf16x8 kst[4];
#pragma unroll
        for (int c = 0; c < 4; c++)
            kst[c] = *reinterpret_cast<const bf16x8*>(Kp + (size_t)srow[c] * HD + scin[c] * 8);
#pragma unroll
        for (int c = 0; c < 4; c++) {
            int byte = srow[c] * 256 + ((scin[c] * 16) ^ ((srow[c] & 7) << 4));
            *reinterpret_cast<bf16x8*>(lds + byte) = kst[c];
        }
    }

    int cur = 0;
    for (int t = 0; t < TRIPS; ++t) {
        __syncthreads();            // buf[cur] ready for all waves
        int kv0 = t * 64;
        bool havenext = (t + 1 < TRIPS);

        // issue next-tile staged loads early (latency hides under compute)
        bf16x8 kst[4];
        if (havenext) {
#pragma unroll
            for (int c = 0; c < 4; c++)
                kst[c] = *reinterpret_cast<const bf16x8*>(Kp + (size_t)(kv0 + 64 + srow[c]) * HD + scin[c] * 8);
        }

        if (kv0 <= wq0 + 31) {
            char* kb_c = lds + cur * 16384;
            // ---- QK^T: S[32][64] ----
            f32x4 s[2][4] = {};
#pragma unroll
            for (int kb = 0; kb < 4; kb++) {
#pragma unroll
                for (int j = 0; j < 4; j++) {
                    int row = j * 16 + lr;
                    int cin = ((kb * 4 + g) ^ (row & 7));
                    bf16x8 kf = *reinterpret_cast<const bf16x8*>(kb_c + row * 256 + cin * 16);
                    s[0][j] = MFMA16(qf[0][kb], kf, s[0][j], 0, 0, 0);
                    s[1][j] = MFMA16(qf[1][kb], kf, s[1][j], 0, 0, 0);
                }
            }

            // ---- online softmax ----
#pragma unroll
            for (int f = 0; f < 2; f++) {
#pragma unroll
                for (int r = 0; r < 4; r++) {
                    int q = wq0 + f * 16 + orow + r;
                    float v0 = (kv0 + 0 * 16 + lr <= q) ? s[f][0][r] : -1e30f;
                    float v1 = (kv0 + 1 * 16 + lr <= q) ? s[f][1][r] : -1e30f;
                    float v2 = (kv0 + 2 * 16 + lr <= q) ? s[f][2][r] : -1e30f;
                    float v3 = (kv0 + 3 * 16 + lr <= q) ? s[f][3][r] : -1e30f;
                    float mx = fmaxf(fmaxf(v0, v1), fmaxf(v2, v3));
#pragma unroll
                    for (int d = 1; d < 16; d <<= 1) mx = fmaxf(mx, __shfl_xor(mx, d));
                    float mn = fmaxf(m[f][r], mx);
                    float sc = __expf(m[f][r] - mn);
                    m[f][r] = mn;
                    float p0 = __expf(v0 - mn);
                    float p1 = __expf(v1 - mn);
                    float p2 = __expf(v2 - mn);
                    float p3 = __expf(v3 - mn);
                    float rs = (p0 + p1) + (p2 + p3);
#pragma unroll
                    for (int d = 1; d < 16; d <<= 1) rs += __shfl_xor(rs, d);
                    l[f][r] = l[f][r] * sc + rs;
#pragma unroll
                    for (int db = 0; db < 8; db++) oacc[f][db][r] *= sc;
                    int row = f * 16 + orow + r;
                    int rb = row * 128;
                    int sw = (row & 7) << 4;
                    *reinterpret_cast<unsigned short*>(pl + rb + ((0 * 32 + lr * 2) ^ sw)) = f2b(p0);
                    *reinterpret_cast<unsigned short*>(pl + rb + ((1 * 32 + lr * 2) ^ sw)) = f2b(p1);
                    *reinterpret_cast<unsigned short*>(pl + rb + ((2 * 32 + lr * 2) ^ sw)) = f2b(p2);
                    *reinterpret_cast<unsigned short*>(pl + rb + ((3 * 32 + lr * 2) ^ sw)) = f2b(p3);
                }
            }

            asm volatile("s_waitcnt lgkmcnt(0)" ::: "memory");
            __builtin_amdgcn_sched_barrier(0);

            // ---- P fragments + PV ----
            bf16x8 pf[2][2];
#pragma unroll
            for (int f = 0; f < 2; f++)
#pragma unroll
                for (int ks = 0; ks < 2; ks++) {
                    int row = f * 16 + lr;
                    int off = row * 128 + (((ks * 4 + g) * 16) ^ ((row & 7) << 4));
                    pf[f][ks] = *reinterpret_cast<const bf16x8*>(pl + off);
                }
#pragma unroll
            for (int db = 0; db < 8; db++) {
#pragma unroll
                for (int ks = 0; ks < 2; ks++) {
                    bf16x8 vf = *reinterpret_cast<const bf16x8*>(Vp + (size_t)(db * 16 + lr) * SEQ + kv0 + ks * 32 + lk);
                    oacc[0][db] = MFMA16(pf[0][ks], vf, oacc[0][db], 0, 0, 0);
                    oacc[1][db] = MFMA16(pf[1][ks], vf, oacc[1][db], 0, 0, 0);
                }
            }
        }

        if (havenext) {
            char* nb_c = lds + (cur ^ 1) * 16384;
#pragma unroll
            for (int c = 0; c < 4; c++) {
                int byte = srow[c] * 256 + ((scin[c] * 16) ^ ((srow[c] & 7) << 4));
                *reinterpret_cast<bf16x8*>(nb_c + byte) = kst[c];
            }
        }
        cur ^= 1;
    }

    // epilogue
    int b = bh >> 4;
    int h = bh & 15;
#pragma unroll
    for (int f = 0; f < 2; f++)
#pragma unroll
        for (int r = 0; r < 4; r++) {
            float inv = 1.0f / l[f][r];
            int srow2 = wq0 + f * 16 + orow + r;
            unsigned short* op = O + ((size_t)(b * SEQ + srow2)) * DMODEL + h * HD;
#pragma unroll
            for (int db = 0; db < 8; db++)
                op[db * 16 + lr] = f2b(oacc[f][db][r] * inv);
        }
}

extern "C" void kernel_launch(void* const* d_in, const int* in_sizes, int n_in,
                              void* d_out, int out_size, void* d_ws, size_t ws_size,
                              hipStream_t stream) {
    const float* x   = (const float*)d_in[0];
    const float* wqk = (const float*)d_in[1];
    const float* wv  = (const float*)d_in[2];
    const float* wo  = (const float*)d_in[3];

    unsigned short* xb  = (unsigned short*)d_ws;            // [4096][2048]
    unsigned short* wb  = xb  + (size_t)8388608;            // [8192][2048]: wqk | wv | wo
    unsigned short* qkv = wb  + (size_t)16777216;           // [4096][6144]
    unsigned short* qb  = qkv + (size_t)25165824;           // [B][H][S][HD]
    unsigned short* kb  = qb  + (size_t)8388608;
    unsigned short* vt  = kb  + (size_t)8388608;            // [B][H][HD][S]
    unsigned short* ao  = vt  + (size_t)8388608;            // [4096][2048]

    cast_f2b<<<8192, 256, 0, stream>>>(x,   xb, 8388608);
    cast_f2b<<<8192, 256, 0, stream>>>(wqk, wb, 8388608);
    cast_f2b<<<4096, 256, 0, stream>>>(wv,  wb + 8388608, 4194304);
    cast_f2b<<<4096, 256, 0, stream>>>(wo,  wb + 12582912, 4194304);

    gemm_bt<1><<<dim3(48, 32), 256, 0, stream>>>(xb, wb, (void*)qkv, 4096, 6144, 2048);

    rope_qk<<<16384, 256, 0, stream>>>(qkv, qb, kb);
    v_rearr<<<8192, 256, 0, stream>>>(qkv, vt);

    attn2<<<512, 256, 0, stream>>>(qb, kb, vt, ao);

    gemm_bt<0><<<dim3(16, 32), 256, 0, stream>>>(ao, wb + 12582912, d_out, 4096, 2048, 2048);
}

// Round 5
// 496.178 us; speedup vs baseline: 2.0035x; 1.5608x over previous
//
#include <hip/hip_runtime.h>
#include <hip/hip_bf16.h>

#define NB 2
#define SEQ 2048
#define DMODEL 2048
#define NH 16
#define HD 128
#define SM_SCALE 0.08838834764831845f

using bf16x8 = __attribute__((ext_vector_type(8))) __bf16;
using f32x4  = __attribute__((ext_vector_type(4))) float;

#define MFMA16 __builtin_amdgcn_mfma_f32_16x16x32_bf16

typedef __attribute__((address_space(1))) const void* gptr_t;
typedef __attribute__((address_space(3))) void* lptr_t;

__device__ inline void gload_lds16(const unsigned short* g, unsigned short* l) {
    __builtin_amdgcn_global_load_lds((gptr_t)g, (lptr_t)l, 16, 0, 0);
}

__device__ inline unsigned short f2b(float f) {
    unsigned u = __builtin_bit_cast(unsigned, f);
    u += 0x7FFF + ((u >> 16) & 1);
    return (unsigned short)(u >> 16);
}
__device__ inline float b2f(unsigned short h) {
    return __builtin_bit_cast(float, (unsigned)h << 16);
}

// ---------------- cast fp32 -> bf16, 4 elems/thread ----------------
__global__ void cast_f2b(const float* __restrict__ src, unsigned short* __restrict__ dst, int n) {
    int i = (blockIdx.x * 256 + threadIdx.x) * 4;
    if (i + 3 < n) {
        float4 v = *reinterpret_cast<const float4*>(src + i);
        ushort4 o;
        o.x = f2b(v.x); o.y = f2b(v.y); o.z = f2b(v.z); o.w = f2b(v.w);
        *reinterpret_cast<ushort4*>(dst + i) = o;
    }
}

// ---------------- GEMM (m97 structure): C[M,N] = A[M,K] * Bw[N,K]^T ----------------
// 128x128 block tile, BK=32, LDS-staged via global_load_lds width=16 (linear dest,
// pre-swizzled global source: chunk kc holds global k-chunk kc ^ ((row>>1)&3)).
template<int OUT_BF16>
__global__ __launch_bounds__(256) void gemm_lds(const unsigned short* __restrict__ A,
                                                const unsigned short* __restrict__ Bw,
                                                void* __restrict__ Cout,
                                                int M, int N, int K) {
    __shared__ __align__(16) unsigned short As[128 * 32];
    __shared__ __align__(16) unsigned short Bs[128 * 32];
    int tid = threadIdx.x;
    int lane = tid & 63;
    int w = tid >> 6;
    int row0 = blockIdx.y * 128;
    int col0 = blockIdx.x * 128;

    // staging: tile = 512 x 16B chunks; wave w, round j covers chunks j*256 + w*64 + lane
    const unsigned short *pA[2], *pB[2];
    unsigned short *lA[2], *lB[2];
#pragma unroll
    for (int j = 0; j < 2; j++) {
        int c = j * 256 + w * 64 + lane;
        int row = c >> 2;                       // 4 chunks (64B = 32 bf16) per row
        int kc = c & 3;
        int ks = kc ^ ((row >> 1) & 3);         // source pre-swizzle
        pA[j] = A  + (size_t)(row0 + row) * K + ks * 8;
        pB[j] = Bw + (size_t)(col0 + row) * K + ks * 8;
        int basechunk = j * 256 + w * 64;       // wave-uniform LDS base (HW adds lane*16B)
        lA[j] = As + basechunk * 8;
        lB[j] = Bs + basechunk * 8;
    }

    int wr = w >> 1, wc = w & 1;
    int lr = lane & 15, g = lane >> 4;
    int offA[4], offB[4];
#pragma unroll
    for (int i = 0; i < 4; i++) {
        int ra = wr * 64 + i * 16 + lr;
        offA[i] = ra * 32 + (g ^ ((ra >> 1) & 3)) * 8;   // read-side swizzle (same XOR)
        int rb = wc * 64 + i * 16 + lr;
        offB[i] = rb * 32 + (g ^ ((rb >> 1) & 3)) * 8;
    }

    f32x4 acc[4][4] = {};

    for (int k = 0; k < K; k += 32) {
#pragma unroll
        for (int j = 0; j < 2; j++) {
            gload_lds16(pA[j] + k, lA[j]);
            gload_lds16(pB[j] + k, lB[j]);
        }
        __syncthreads();                        // drains vmcnt -> tiles visible

        bf16x8 a[4], b[4];
#pragma unroll
        for (int i = 0; i < 4; i++) a[i] = *reinterpret_cast<const bf16x8*>(As + offA[i]);
#pragma unroll
        for (int j2 = 0; j2 < 4; j2++) b[j2] = *reinterpret_cast<const bf16x8*>(Bs + offB[j2]);
#pragma unroll
        for (int i = 0; i < 4; i++)
#pragma unroll
            for (int j2 = 0; j2 < 4; j2++)
                acc[i][j2] = MFMA16(a[i], b[j2], acc[i][j2], 0, 0, 0);
        __syncthreads();                        // reads done before next stage overwrites
    }

    int orow = g * 4;
#pragma unroll
    for (int i = 0; i < 4; i++) {
#pragma unroll
        for (int j = 0; j < 4; j++) {
            int r0 = row0 + wr * 64 + i * 16 + orow;
            int c  = col0 + wc * 64 + j * 16 + lr;
#pragma unroll
            for (int r = 0; r < 4; r++) {
                float v = acc[i][j][r];
                if (OUT_BF16)
                    ((unsigned short*)Cout)[(size_t)(r0 + r) * N + c] = f2b(v);
                else
                    ((float*)Cout)[(size_t)(r0 + r) * N + c] = v;
            }
        }
    }
}

// ---------------- RoPE + rearrange Q,K ----------------
__global__ void rope_qk(const unsigned short* __restrict__ qkv,
                        unsigned short* __restrict__ qb,
                        unsigned short* __restrict__ kb) {
    int idx = blockIdx.x * 256 + threadIdx.x;
    int i = idx & 63;
    int h = (idx >> 6) & 15;
    int t = idx >> 10;
    int s = t & (SEQ - 1);
    int b = t >> 11;

    float inv = exp2f(-13.287712379549449f * (float)i * (1.0f / 64.0f));
    float ang = (float)s * inv;
    float sn, cs;
    sincosf(ang, &sn, &cs);

    const unsigned short* base = qkv + (size_t)t * 6144 + h * 128 + 2 * i;
    unsigned qv = *reinterpret_cast<const unsigned*>(base);
    unsigned kv = *reinterpret_cast<const unsigned*>(base + 2048);

    float qe = b2f((unsigned short)(qv & 0xFFFF));
    float qo = b2f((unsigned short)(qv >> 16));
    float ke = b2f((unsigned short)(kv & 0xFFFF));
    float ko = b2f((unsigned short)(kv >> 16));

    float qe2 = (qe * cs - qo * sn) * SM_SCALE;
    float qo2 = (qe * sn + qo * cs) * SM_SCALE;
    float ke2 = ke * cs - ko * sn;
    float ko2 = ke * sn + ko * cs;

    size_t o = ((size_t)(b * NH + h) * SEQ + s) * HD + 2 * i;
    *reinterpret_cast<unsigned*>(qb + o) = (unsigned)f2b(qe2) | ((unsigned)f2b(qo2) << 16);
    *reinterpret_cast<unsigned*>(kb + o) = (unsigned)f2b(ke2) | ((unsigned)f2b(ko2) << 16);
}

// ---------------- V rearrange: qkv -> vt [B][H][HD][S] ----------------
__global__ void v_rearr(const unsigned short* __restrict__ qkv, unsigned short* __restrict__ vt) {
    int idx = blockIdx.x * 256 + threadIdx.x;
    int s4 = (idx & 511) * 4;
    int d  = (idx >> 9) & 127;
    int h  = (idx >> 16) & 15;
    int b  = idx >> 20;
    ushort4 o;
    size_t rbase = (size_t)(b * SEQ + s4) * 6144 + 4096 + h * 128 + d;
    o.x = qkv[rbase];
    o.y = qkv[rbase + 6144];
    o.z = qkv[rbase + 2 * 6144];
    o.w = qkv[rbase + 3 * 6144];
    *reinterpret_cast<ushort4*>(vt + ((size_t)(b * NH + h) * HD + d) * SEQ + s4) = o;
}

// ---------------- flash attention v2 (unchanged from round 3) ----------------
__global__ __launch_bounds__(256) void attn2(const unsigned short* __restrict__ Q,
                                             const unsigned short* __restrict__ Kb,
                                             const unsigned short* __restrict__ Vt,
                                             unsigned short* __restrict__ O) {
    __shared__ __align__(16) char lds[49152];

    int tid = threadIdx.x;
    int lane = tid & 63;
    int w = tid >> 6;
    int bid = blockIdx.x;
    int qblk = (bid < 256) ? (15 - (bid >> 5)) : ((bid - 256) >> 5);
    int bh = bid & 31;
    int wq0 = qblk * 128 + w * 32;
    int lr = lane & 15;
    int g  = lane >> 4;
    int lk = g * 8;
    int orow = g * 4;

    const unsigned short* Qp = Q  + (size_t)bh * SEQ * HD;
    const unsigned short* Kp = Kb + (size_t)bh * SEQ * HD;
    const unsigned short* Vp = Vt + (size_t)bh * HD * SEQ;
    char* pl = lds + 32768 + w * 4096;

    bf16x8 qf[2][4];
#pragma unroll
    for (int f = 0; f < 2; f++)
#pragma unroll
        for (int kb = 0; kb < 4; kb++)
            qf[f][kb] = *reinterpret_cast<const bf16x8*>(Qp + (size_t)(wq0 + f * 16 + lr) * HD + kb * 32 + lk);

    f32x4 oacc[2][8] = {};
    float m[2][4], l[2][4];
#pragma unroll
    for (int f = 0; f < 2; f++)
#pragma unroll
        for (int r = 0; r < 4; r++) { m[f][r] = -1e30f; l[f][r] = 0.0f; }

    int TRIPS = 2 * qblk + 2;

    int srow[4], scin[4];
#pragma unroll
    for (int c = 0; c < 4; c++) {
        int chunk = tid + c * 256;
        srow[c] = chunk >> 4;
        scin[c] = chunk & 15;
    }

    {
        bf16x8 kst[4];
#pragma unroll
        for (int c = 0; c < 4; c++)
            kst[c] = *reinterpret_cast<const bf16x8*>(Kp + (size_t)srow[c] * HD + scin[c] * 8);
#pragma unroll
        for (int c = 0; c < 4; c++) {
            int byte = srow[c] * 256 + ((scin[c] * 16) ^ ((srow[c] & 7) << 4));
            *reinterpret_cast<bf16x8*>(lds + byte) = kst[c];
        }
    }

    int cur = 0;
    for (int t = 0; t < TRIPS; ++t) {
        __syncthreads();
        int kv0 = t * 64;
        bool havenext = (t + 1 < TRIPS);

        bf16x8 kst[4];
        if (havenext) {
#pragma unroll
            for (int c = 0; c < 4; c++)
                kst[c] = *reinterpret_cast<const bf16x8*>(Kp + (size_t)(kv0 + 64 + srow[c]) * HD + scin[c] * 8);
        }

        if (kv0 <= wq0 + 31) {
            char* kb_c = lds + cur * 16384;
            f32x4 s[2][4] = {};
#pragma unroll
            for (int kb = 0; kb < 4; kb++) {
#pragma unroll
                for (int j = 0; j < 4; j++) {
                    int row = j * 16 + lr;
                    int cin = ((kb * 4 + g) ^ (row & 7));
                    bf16x8 kf = *reinterpret_cast<const bf16x8*>(kb_c + row * 256 + cin * 16);
                    s[0][j] = MFMA16(qf[0][kb], kf, s[0][j], 0, 0, 0);
                    s[1][j] = MFMA16(qf[1][kb], kf, s[1][j], 0, 0, 0);
                }
            }

#pragma unroll
            for (int f = 0; f < 2; f++) {
#pragma unroll
                for (int r = 0; r < 4; r++) {
                    int q = wq0 + f * 16 + orow + r;
                    float v0 = (kv0 + 0 * 16 + lr <= q) ? s[f][0][r] : -1e30f;
                    float v1 = (kv0 + 1 * 16 + lr <= q) ? s[f][1][r] : -1e30f;
                    float v2 = (kv0 + 2 * 16 + lr <= q) ? s[f][2][r] : -1e30f;
                    float v3 = (kv0 + 3 * 16 + lr <= q) ? s[f][3][r] : -1e30f;
                    float mx = fmaxf(fmaxf(v0, v1), fmaxf(v2, v3));
#pragma unroll
                    for (int d = 1; d < 16; d <<= 1) mx = fmaxf(mx, __shfl_xor(mx, d));
                    float mn = fmaxf(m[f][r], mx);
                    float sc = __expf(m[f][r] - mn);
                    m[f][r] = mn;
                    float p0 = __expf(v0 - mn);
                    float p1 = __expf(v1 - mn);
                    float p2 = __expf(v2 - mn);
                    float p3 = __expf(v3 - mn);
                    float rs = (p0 + p1) + (p2 + p3);
#pragma unroll
                    for (int d = 1; d < 16; d <<= 1) rs += __shfl_xor(rs, d);
                    l[f][r] = l[f][r] * sc + rs;
#pragma unroll
                    for (int db = 0; db < 8; db++) oacc[f][db][r] *= sc;
                    int row = f * 16 + orow + r;
                    int rb = row * 128;
                    int sw = (row & 7) << 4;
                    *reinterpret_cast<unsigned short*>(pl + rb + ((0 * 32 + lr * 2) ^ sw)) = f2b(p0);
                    *reinterpret_cast<unsigned short*>(pl + rb + ((1 * 32 + lr * 2) ^ sw)) = f2b(p1);
                    *reinterpret_cast<unsigned short*>(pl + rb + ((2 * 32 + lr * 2) ^ sw)) = f2b(p2);
                    *reinterpret_cast<unsigned short*>(pl + rb + ((3 * 32 + lr * 2) ^ sw)) = f2b(p3);
                }
            }

            asm volatile("s_waitcnt lgkmcnt(0)" ::: "memory");
            __builtin_amdgcn_sched_barrier(0);

            bf16x8 pf[2][2];
#pragma unroll
            for (int f = 0; f < 2; f++)
#pragma unroll
                for (int ks = 0; ks < 2; ks++) {
                    int row = f * 16 + lr;
                    int off = row * 128 + (((ks * 4 + g) * 16) ^ ((row & 7) << 4));
                    pf[f][ks] = *reinterpret_cast<const bf16x8*>(pl + off);
                }
#pragma unroll
            for (int db = 0; db < 8; db++) {
#pragma unroll
                for (int ks = 0; ks < 2; ks++) {
                    bf16x8 vf = *reinterpret_cast<const bf16x8*>(Vp + (size_t)(db * 16 + lr) * SEQ + kv0 + ks * 32 + lk);
                    oacc[0][db] = MFMA16(pf[0][ks], vf, oacc[0][db], 0, 0, 0);
                    oacc[1][db] = MFMA16(pf[1][ks], vf, oacc[1][db], 0, 0, 0);
                }
            }
        }

        if (havenext) {
            char* nb_c = lds + (cur ^ 1) * 16384;
#pragma unroll
            for (int c = 0; c < 4; c++) {
                int byte = srow[c] * 256 + ((scin[c] * 16) ^ ((srow[c] & 7) << 4));
                *reinterpret_cast<bf16x8*>(nb_c + byte) = kst[c];
            }
        }
        cur ^= 1;
    }

    int b = bh >> 4;
    int h = bh & 15;
#pragma unroll
    for (int f = 0; f < 2; f++)
#pragma unroll
        for (int r = 0; r < 4; r++) {
            float inv = 1.0f / l[f][r];
            int srow2 = wq0 + f * 16 + orow + r;
            unsigned short* op = O + ((size_t)(b * SEQ + srow2)) * DMODEL + h * HD;
#pragma unroll
            for (int db = 0; db < 8; db++)
                op[db * 16 + lr] = f2b(oacc[f][db][r] * inv);
        }
}

extern "C" void kernel_launch(void* const* d_in, const int* in_sizes, int n_in,
                              void* d_out, int out_size, void* d_ws, size_t ws_size,
                              hipStream_t stream) {
    const float* x   = (const float*)d_in[0];
    const float* wqk = (const float*)d_in[1];
    const float* wv  = (const float*)d_in[2];
    const float* wo  = (const float*)d_in[3];

    unsigned short* xb  = (unsigned short*)d_ws;            // [4096][2048]
    unsigned short* wb  = xb  + (size_t)8388608;            // [8192][2048]: wqk | wv | wo
    unsigned short* qkv = wb  + (size_t)16777216;           // [4096][6144]
    unsigned short* qb  = qkv + (size_t)25165824;           // [B][H][S][HD]
    unsigned short* kb  = qb  + (size_t)8388608;
    unsigned short* vt  = kb  + (size_t)8388608;            // [B][H][HD][S]
    unsigned short* ao  = vt  + (size_t)8388608;            // [4096][2048]

    cast_f2b<<<8192, 256, 0, stream>>>(x,   xb, 8388608);
    cast_f2b<<<8192, 256, 0, stream>>>(wqk, wb, 8388608);
    cast_f2b<<<4096, 256, 0, stream>>>(wv,  wb + 8388608, 4194304);
    cast_f2b<<<4096, 256, 0, stream>>>(wo,  wb + 12582912, 4194304);

    gemm_lds<1><<<dim3(48, 32), 256, 0, stream>>>(xb, wb, (void*)qkv, 4096, 6144, 2048);

    rope_qk<<<16384, 256, 0, stream>>>(qkv, qb, kb);
    v_rearr<<<8192, 256, 0, stream>>>(qkv, vt);

    attn2<<<512, 256, 0, stream>>>(qb, kb, vt, ao);

    gemm_lds<0><<<dim3(16, 32), 256, 0, stream>>>(ao, wb + 12582912, d_out, 4096, 2048, 2048);
}

// Round 7
// 405.961 us; speedup vs baseline: 2.4487x; 1.2222x over previous
//
#include <hip/hip_runtime.h>
#include <hip/hip_bf16.h>

#define NB 2
#define SEQ 2048
#define DMODEL 2048
#define NH 16
#define HD 128
#define SM_SCALE 0.08838834764831845f

using bf16x8 = __attribute__((ext_vector_type(8))) __bf16;
using f32x4  = __attribute__((ext_vector_type(4))) float;

#define MFMA16 __builtin_amdgcn_mfma_f32_16x16x32_bf16

typedef __attribute__((address_space(1))) const void* gptr_t;
typedef __attribute__((address_space(3))) void* lptr_t;

__device__ inline void gload_lds16(const unsigned short* g, unsigned short* l) {
    __builtin_amdgcn_global_load_lds((gptr_t)g, (lptr_t)l, 16, 0, 0);
}

__device__ inline unsigned short f2b(float f) {
    unsigned u = __builtin_bit_cast(unsigned, f);
    u += 0x7FFF + ((u >> 16) & 1);
    return (unsigned short)(u >> 16);
}
__device__ inline float b2f(unsigned short h) {
    return __builtin_bit_cast(float, (unsigned)h << 16);
}

// ---------------- cast fp32 -> bf16, 4 elems/thread ----------------
__global__ void cast_f2b(const float* __restrict__ src, unsigned short* __restrict__ dst, int n) {
    int i = (blockIdx.x * 256 + threadIdx.x) * 4;
    if (i + 3 < n) {
        float4 v = *reinterpret_cast<const float4*>(src + i);
        ushort4 o;
        o.x = f2b(v.x); o.y = f2b(v.y); o.z = f2b(v.z); o.w = f2b(v.w);
        *reinterpret_cast<ushort4*>(dst + i) = o;
    }
}

// ---------------- GEMM (m97 structure, unchanged from round 4) ----------------
template<int OUT_BF16>
__global__ __launch_bounds__(256) void gemm_lds(const unsigned short* __restrict__ A,
                                                const unsigned short* __restrict__ Bw,
                                                void* __restrict__ Cout,
                                                int M, int N, int K) {
    __shared__ __align__(16) unsigned short As[128 * 32];
    __shared__ __align__(16) unsigned short Bs[128 * 32];
    int tid = threadIdx.x;
    int lane = tid & 63;
    int w = tid >> 6;
    int row0 = blockIdx.y * 128;
    int col0 = blockIdx.x * 128;

    const unsigned short *pA[2], *pB[2];
    unsigned short *lA[2], *lB[2];
#pragma unroll
    for (int j = 0; j < 2; j++) {
        int c = j * 256 + w * 64 + lane;
        int row = c >> 2;
        int kc = c & 3;
        int ks = kc ^ ((row >> 1) & 3);
        pA[j] = A  + (size_t)(row0 + row) * K + ks * 8;
        pB[j] = Bw + (size_t)(col0 + row) * K + ks * 8;
        int basechunk = j * 256 + w * 64;
        lA[j] = As + basechunk * 8;
        lB[j] = Bs + basechunk * 8;
    }

    int wr = w >> 1, wc = w & 1;
    int lr = lane & 15, g = lane >> 4;
    int offA[4], offB[4];
#pragma unroll
    for (int i = 0; i < 4; i++) {
        int ra = wr * 64 + i * 16 + lr;
        offA[i] = ra * 32 + (g ^ ((ra >> 1) & 3)) * 8;
        int rb = wc * 64 + i * 16 + lr;
        offB[i] = rb * 32 + (g ^ ((rb >> 1) & 3)) * 8;
    }

    f32x4 acc[4][4] = {};

    for (int k = 0; k < K; k += 32) {
#pragma unroll
        for (int j = 0; j < 2; j++) {
            gload_lds16(pA[j] + k, lA[j]);
            gload_lds16(pB[j] + k, lB[j]);
        }
        __syncthreads();

        bf16x8 a[4], b[4];
#pragma unroll
        for (int i = 0; i < 4; i++) a[i] = *reinterpret_cast<const bf16x8*>(As + offA[i]);
#pragma unroll
        for (int j2 = 0; j2 < 4; j2++) b[j2] = *reinterpret_cast<const bf16x8*>(Bs + offB[j2]);
#pragma unroll
        for (int i = 0; i < 4; i++)
#pragma unroll
            for (int j2 = 0; j2 < 4; j2++)
                acc[i][j2] = MFMA16(a[i], b[j2], acc[i][j2], 0, 0, 0);
        __syncthreads();
    }

    int orow = g * 4;
#pragma unroll
    for (int i = 0; i < 4; i++) {
#pragma unroll
        for (int j = 0; j < 4; j++) {
            int r0 = row0 + wr * 64 + i * 16 + orow;
            int c  = col0 + wc * 64 + j * 16 + lr;
#pragma unroll
            for (int r = 0; r < 4; r++) {
                float v = acc[i][j][r];
                if (OUT_BF16)
                    ((unsigned short*)Cout)[(size_t)(r0 + r) * N + c] = f2b(v);
                else
                    ((float*)Cout)[(size_t)(r0 + r) * N + c] = v;
            }
        }
    }
}

// ---------------- RoPE + rearrange Q,K ----------------
__global__ void rope_qk(const unsigned short* __restrict__ qkv,
                        unsigned short* __restrict__ qb,
                        unsigned short* __restrict__ kb) {
    int idx = blockIdx.x * 256 + threadIdx.x;
    int i = idx & 63;
    int h = (idx >> 6) & 15;
    int t = idx >> 10;
    int s = t & (SEQ - 1);
    int b = t >> 11;

    float inv = exp2f(-13.287712379549449f * (float)i * (1.0f / 64.0f));
    float ang = (float)s * inv;
    float sn, cs;
    sincosf(ang, &sn, &cs);

    const unsigned short* base = qkv + (size_t)t * 6144 + h * 128 + 2 * i;
    unsigned qv = *reinterpret_cast<const unsigned*>(base);
    unsigned kv = *reinterpret_cast<const unsigned*>(base + 2048);

    float qe = b2f((unsigned short)(qv & 0xFFFF));
    float qo = b2f((unsigned short)(qv >> 16));
    float ke = b2f((unsigned short)(kv & 0xFFFF));
    float ko = b2f((unsigned short)(kv >> 16));

    float qe2 = (qe * cs - qo * sn) * SM_SCALE;
    float qo2 = (qe * sn + qo * cs) * SM_SCALE;
    float ke2 = ke * cs - ko * sn;
    float ko2 = ke * sn + ko * cs;

    size_t o = ((size_t)(b * NH + h) * SEQ + s) * HD + 2 * i;
    *reinterpret_cast<unsigned*>(qb + o) = (unsigned)f2b(qe2) | ((unsigned)f2b(qo2) << 16);
    *reinterpret_cast<unsigned*>(kb + o) = (unsigned)f2b(ke2) | ((unsigned)f2b(ko2) << 16);
}

// ---------------- V rearrange: qkv -> vt [B][H][HD][S] ----------------
__global__ void v_rearr(const unsigned short* __restrict__ qkv, unsigned short* __restrict__ vt) {
    int idx = blockIdx.x * 256 + threadIdx.x;
    int s4 = (idx & 511) * 4;
    int d  = (idx >> 9) & 127;
    int h  = (idx >> 16) & 15;
    int b  = idx >> 20;
    ushort4 o;
    size_t rbase = (size_t)(b * SEQ + s4) * 6144 + 4096 + h * 128 + d;
    o.x = qkv[rbase];
    o.y = qkv[rbase + 6144];
    o.z = qkv[rbase + 2 * 6144];
    o.w = qkv[rbase + 3 * 6144];
    *reinterpret_cast<ushort4*>(vt + ((size_t)(b * NH + h) * HD + d) * SEQ + s4) = o;
}

// ---------------- flash attention v3: swapped-operand softmax ----------------
// QK^T as mfma(K,Q): lane owns q = lane&15, kv = j*16 + g*4 + r  (in-lane row slice)
// PV  as mfma(V^T,P): output q = lane&15 (rescale/div in-lane), d = db*16+g*4+r
__global__ __launch_bounds__(256) void attn3(const unsigned short* __restrict__ Q,
                                             const unsigned short* __restrict__ Kb,
                                             const unsigned short* __restrict__ Vt,
                                             unsigned short* __restrict__ O) {
    __shared__ __align__(16) char lds[49152];   // 2x16KB K dbuf + 4x4KB P

    int tid = threadIdx.x;
    int lane = tid & 63;
    int w = tid >> 6;
    int bid = blockIdx.x;
    int qblk = (bid < 256) ? (15 - (bid >> 5)) : ((bid - 256) >> 5);
    int bh = bid & 31;
    int wq0 = qblk * 128 + w * 32;
    int lr = lane & 15;
    int g  = lane >> 4;
    int g4 = g * 4;
    int lk = g * 8;

    const unsigned short* Qp = Q  + (size_t)bh * SEQ * HD;
    const unsigned short* Kp = Kb + (size_t)bh * SEQ * HD;
    const unsigned short* Vp = Vt + (size_t)bh * HD * SEQ;
    char* pl = lds + 32768 + w * 4096;

    // Q fragments: B-operand, rows q = wq0 + f*16 + lr
    bf16x8 qf[2][4];
#pragma unroll
    for (int f = 0; f < 2; f++)
#pragma unroll
        for (int kb = 0; kb < 4; kb++)
            qf[f][kb] = *reinterpret_cast<const bf16x8*>(Qp + (size_t)(wq0 + f * 16 + lr) * HD + kb * 32 + lk);

    f32x4 oacc[2][8] = {};
    float m[2], l[2];
#pragma unroll
    for (int f = 0; f < 2; f++) { m[f] = -1e30f; l[f] = 0.0f; }
    int qrow[2] = { wq0 + lr, wq0 + 16 + lr };

    int TRIPS = 2 * qblk + 2;

    int srow[4], scin[4];
#pragma unroll
    for (int c = 0; c < 4; c++) {
        int chunk = tid + c * 256;
        srow[c] = chunk >> 4;
        scin[c] = chunk & 15;
    }

    // prologue: stage K tile 0 into buf 0
    {
        bf16x8 kst[4];
#pragma unroll
        for (int c = 0; c < 4; c++)
            kst[c] = *reinterpret_cast<const bf16x8*>(Kp + (size_t)srow[c] * HD + scin[c] * 8);
#pragma unroll
        for (int c = 0; c < 4; c++) {
            int byte = srow[c] * 256 + ((scin[c] * 16) ^ ((srow[c] & 7) << 4));
            *reinterpret_cast<bf16x8*>(lds + byte) = kst[c];
        }
    }

    int cur = 0;
    for (int t = 0; t < TRIPS; ++t) {
        __syncthreads();
        int kv0 = t * 64;
        bool havenext = (t + 1 < TRIPS);

        bf16x8 kst[4];
        if (havenext) {
#pragma unroll
            for (int c = 0; c < 4; c++)
                kst[c] = *reinterpret_cast<const bf16x8*>(Kp + (size_t)(kv0 + 64 + srow[c]) * HD + scin[c] * 8);
        }

        if (kv0 <= wq0 + 31) {
            char* kb_c = lds + cur * 16384;
            // ---- QK^T swapped: s[f][j] = K_j * Q_f ----
            f32x4 s[2][4] = {};
#pragma unroll
            for (int kb = 0; kb < 4; kb++) {
#pragma unroll
                for (int j = 0; j < 4; j++) {
                    int row = j * 16 + lr;
                    int cin = ((kb * 4 + g) ^ (row & 7));
                    bf16x8 kf = *reinterpret_cast<const bf16x8*>(kb_c + row * 256 + cin * 16);
                    s[0][j] = MFMA16(kf, qf[0][kb], s[0][j], 0, 0, 0);
                    s[1][j] = MFMA16(kf, qf[1][kb], s[1][j], 0, 0, 0);
                }
            }

            // ---- V prefetch (independent of softmax; issue early) ----
            bf16x8 vf[8][2];
#pragma unroll
            for (int db = 0; db < 8; db++)
#pragma unroll
                for (int ks = 0; ks < 2; ks++)
                    vf[db][ks] = *reinterpret_cast<const bf16x8*>(Vp + (size_t)(db * 16 + lr) * SEQ + kv0 + ks * 32 + lk);

            // ---- in-lane online softmax ----
#pragma unroll
            for (int f = 0; f < 2; f++) {
                int q = qrow[f];   // q = wq0 + f*16 + lr
                float mx = -1e30f;
#pragma unroll
                for (int j = 0; j < 4; j++)
#pragma unroll
                    for (int r = 0; r < 4; r++) {
                        int kv = kv0 + j * 16 + g4 + r;
                        float v = (kv <= q) ? s[f][j][r] : -1e30f;
                        s[f][j][r] = v;
                        mx = fmaxf(mx, v);
                    }
                mx = fmaxf(mx, __shfl_xor(mx, 16));
                mx = fmaxf(mx, __shfl_xor(mx, 32));
                float mn = fmaxf(m[f], mx);
                float sc = __expf(m[f] - mn);
                m[f] = mn;

                int row = f * 16 + lr;
                int rb = row * 128;
                int sw = (row & 7) << 4;
                float rs = 0.0f;
#pragma unroll
                for (int j = 0; j < 4; j++)
#pragma unroll
                    for (int hh = 0; hh < 2; hh++) {
                        float p0 = __expf(s[f][j][2 * hh]     - mn);
                        float p1 = __expf(s[f][j][2 * hh + 1] - mn);
                        rs += p0 + p1;
                        unsigned pk = (unsigned)f2b(p0) | ((unsigned)f2b(p1) << 16);
                        int colb = j * 32 + g * 8 + 4 * hh;
                        *reinterpret_cast<unsigned*>(pl + rb + (colb ^ sw)) = pk;
                    }
                rs += __shfl_xor(rs, 16);
                rs += __shfl_xor(rs, 32);
                l[f] = l[f] * sc + rs;
#pragma unroll
                for (int db = 0; db < 8; db++)
#pragma unroll
                    for (int r = 0; r < 4; r++)
                        oacc[f][db][r] *= sc;
            }

            asm volatile("s_waitcnt lgkmcnt(0)" ::: "memory");
            __builtin_amdgcn_sched_barrier(0);

            // ---- P fragments (B-operand, q = f*16+lr) + swapped PV ----
            bf16x8 pb[2][2];
#pragma unroll
            for (int f = 0; f < 2; f++)
#pragma unroll
                for (int ks = 0; ks < 2; ks++) {
                    int row = f * 16 + lr;
                    int off = row * 128 + ((ks * 64 + g * 16) ^ ((row & 7) << 4));
                    pb[f][ks] = *reinterpret_cast<const bf16x8*>(pl + off);
                }
#pragma unroll
            for (int db = 0; db < 8; db++)
#pragma unroll
                for (int ks = 0; ks < 2; ks++) {
                    oacc[0][db] = MFMA16(vf[db][ks], pb[0][ks], oacc[0][db], 0, 0, 0);
                    oacc[1][db] = MFMA16(vf[db][ks], pb[1][ks], oacc[1][db], 0, 0, 0);
                }
        }

        if (havenext) {
            char* nb_c = lds + (cur ^ 1) * 16384;
#pragma unroll
            for (int c = 0; c < 4; c++) {
                int byte = srow[c] * 256 + ((scin[c] * 16) ^ ((srow[c] & 7) << 4));
                *reinterpret_cast<bf16x8*>(nb_c + byte) = kst[c];
            }
        }
        cur ^= 1;
    }

    // epilogue: O[q = wq0+f*16+lr][d = db*16+g*4+r], div by l in-lane
    int b = bh >> 4;
    int h = bh & 15;
#pragma unroll
    for (int f = 0; f < 2; f++) {
        float inv = 1.0f / l[f];
        int q = wq0 + f * 16 + lr;
        unsigned short* op = O + ((size_t)(b * SEQ + q)) * DMODEL + h * HD;
#pragma unroll
        for (int db = 0; db < 8; db++) {
            ushort4 o4;
            o4.x = f2b(oacc[f][db][0] * inv);
            o4.y = f2b(oacc[f][db][1] * inv);
            o4.z = f2b(oacc[f][db][2] * inv);
            o4.w = f2b(oacc[f][db][3] * inv);
            *reinterpret_cast<ushort4*>(op + db * 16 + g4) = o4;
        }
    }
}

extern "C" void kernel_launch(void* const* d_in, const int* in_sizes, int n_in,
                              void* d_out, int out_size, void* d_ws, size_t ws_size,
                              hipStream_t stream) {
    const float* x   = (const float*)d_in[0];
    const float* wqk = (const float*)d_in[1];
    const float* wv  = (const float*)d_in[2];
    const float* wo  = (const float*)d_in[3];

    unsigned short* xb  = (unsigned short*)d_ws;            // [4096][2048]
    unsigned short* wb  = xb  + (size_t)8388608;            // [8192][2048]: wqk | wv | wo
    unsigned short* qkv = wb  + (size_t)16777216;           // [4096][6144]
    unsigned short* qb  = qkv + (size_t)25165824;           // [B][H][S][HD]
    unsigned short* kb  = qb  + (size_t)8388608;
    unsigned short* vt  = kb  + (size_t)8388608;            // [B][H][HD][S]
    unsigned short* ao  = vt  + (size_t)8388608;            // [4096][2048]

    cast_f2b<<<8192, 256, 0, stream>>>(x,   xb, 8388608);
    cast_f2b<<<8192, 256, 0, stream>>>(wqk, wb, 8388608);
    cast_f2b<<<4096, 256, 0, stream>>>(wv,  wb + 8388608, 4194304);
    cast_f2b<<<4096, 256, 0, stream>>>(wo,  wb + 12582912, 4194304);

    gemm_lds<1><<<dim3(48, 32), 256, 0, stream>>>(xb, wb, (void*)qkv, 4096, 6144, 2048);

    rope_qk<<<16384, 256, 0, stream>>>(qkv, qb, kb);
    v_rearr<<<8192, 256, 0, stream>>>(qkv, vt);

    attn3<<<512, 256, 0, stream>>>(qb, kb, vt, ao);

    gemm_lds<0><<<dim3(16, 32), 256, 0, stream>>>(ao, wb + 12582912, d_out, 4096, 2048, 2048);
}